// Round 8
// baseline (248.785 us; speedup 1.0000x reference)
//
#include <hip/hip_runtime.h>
#include <math.h>

#define BB 4
#define NN 512
#define EE 128
#define NODE_F 16
#define EDGE_F 8
#define LL 3

typedef __attribute__((ext_vector_type(8))) short bf16x8;
typedef __attribute__((ext_vector_type(4))) float f32x4;

__device__ __forceinline__ ushort bf_hi(float x) {
    uint u = __float_as_uint(x);
    return (ushort)((u + 0x7fffu + ((u >> 16) & 1u)) >> 16);
}
__device__ __forceinline__ float bf_f(ushort h) {
    return __uint_as_float(((uint)h) << 16);
}

__global__ __launch_bounds__(512) void k_rows(
    const float* __restrict__ nf,          // B,N,16
    const float* __restrict__ ef,          // B,N,N,8
    const float* __restrict__ W,           // B,N,N
    const int*   __restrict__ assigned,    // B,N
    const int*   __restrict__ open_group,  // B,N
    const int*   __restrict__ action_mask, // B,N
    const float* __restrict__ build_limit, // B,3
    const float* __restrict__ open_group_size, // B,3
    const float* __restrict__ embed_w,     // 22,128
    const float* __restrict__ embed_b,     // 128
    const float* __restrict__ node_w,      // L,128,128
    const float* __restrict__ edge_w,      // L,8,128
    const float* __restrict__ weight_w,    // L,128
    const float* __restrict__ out_w,       // L,128,128
    const float* __restrict__ out_b,       // L,128
    float* __restrict__ hout)              // B*N,128
{
    const int i   = blockIdx.x;
    const int b   = blockIdx.y;
    const int t   = threadIdx.x;
    const int l   = t & 63;                // lane
    const int w   = t >> 6;                // wave 0..7 -> e-tile
    const int e   = t & 127;               // for split-k dots
    const int ks  = t >> 7;                // 0..3, k-slot for dots
    const int row = b * NN + i;

    // A-fragments: [32 j-tiles][64 lanes] x 8 bf16 = 32 KB
    __shared__ bf16x8 afr[32 * 64];
    __shared__ float hsh[EE];
    __shared__ float hipart[4][EE];
    __shared__ float opart[4][EE];
    __shared__ float aggfin[EE];
    __shared__ float xsh[24];

    // ---- x = [node_features(16), assigned, open, mask, ratio(3)] ----
    if (t < NODE_F) {
        xsh[t] = nf[row * NODE_F + t];
    } else if (t == 16) {
        xsh[16] = assigned[row] ? 1.0f : 0.0f;
    } else if (t == 17) {
        xsh[17] = open_group[row] ? 1.0f : 0.0f;
    } else if (t == 18) {
        xsh[18] = action_mask[row] ? 1.0f : 0.0f;
    } else if (t < 22) {
        int k = t - 19;
        xsh[t] = open_group_size[b * 3 + k] / fmaxf(build_limit[b * 3 + k], 1e-6f);
    }

    // ---- pack A-fragments (once; layer-invariant) ----
    // K slots: 0-7: ef_hi  8-15: ef_hi  16-23: ef_lo  24: W_hi 25: W_hi 26: W_lo
    // lane ll of tile jt holds A[j = jt*16 + (ll&15), k = (ll>>4)*8 .. +8]
    {
        const float* efr = ef + (size_t)row * NN * EDGE_F;
        const float* Wr  = W + (size_t)row * NN;
        #pragma unroll
        for (int q = 0; q < 4; ++q) {
            const int eid = t + 512 * q;        // 0..2047
            const int ll  = eid & 63;
            const int jt  = eid >> 6;
            const int g   = ll >> 4;
            const int jj  = jt * 16 + (ll & 15);
            bf16x8 frag;
            if (g < 3) {
                const float4 a = *(const float4*)&efr[jj * 8];
                const float4 c4 = *(const float4*)&efr[jj * 8 + 4];
                float v[8] = {a.x, a.y, a.z, a.w, c4.x, c4.y, c4.z, c4.w};
                if (g < 2) {
                    #pragma unroll
                    for (int m = 0; m < 8; ++m) frag[m] = (short)bf_hi(v[m]);
                } else {
                    #pragma unroll
                    for (int m = 0; m < 8; ++m) {
                        ushort h = bf_hi(v[m]);
                        frag[m] = (short)bf_hi(v[m] - bf_f(h));
                    }
                }
            } else {
                float wv = Wr[jj];
                ushort h = bf_hi(wv);
                ushort lo = bf_hi(wv - bf_f(h));
                frag = (bf16x8){(short)h, (short)h, (short)lo, 0, 0, 0, 0, 0};
            }
            afr[eid] = frag;
        }
    }
    __syncthreads();

    // ---- h0 = x @ embed_w + embed_b ----
    if (t < EE) {
        float h0 = embed_b[t];
        #pragma unroll
        for (int k = 0; k < 22; ++k)
            h0 = fmaf(xsh[k], embed_w[k * EE + t], h0);
        hsh[t] = h0;
    }

    const float c  = 2.8853900817779268f;  // 2*log2(e) folded into weights
    const int  le  = l & 15;
    const int  g   = l >> 4;
    const int  eN  = w * 16 + le;          // this lane's e column

    for (int lay = 0; lay < LL; ++lay) {
        __syncthreads();   // B1: hsh stable, previous layer's LDS reads done

        // ---- hi partial: all 512 threads, k in [ks*32, ks*32+32) ----
        {
            const float* nw = node_w + lay * EE * EE + ks * 32 * EE + e;
            float hp = 0.0f;
            #pragma unroll 8
            for (int k = 0; k < 32; ++k)
                hp = fmaf(hsh[ks * 32 + k], nw[k * EE], hp);
            hipart[ks][e] = hp;
        }

        // ---- B-fragment for this lane (fixed per layer) ----
        // B[k = g*8+m, n = le]:  g0: we_hi  g1: we_lo  g2: we_hi  g3: [wl_hi, wl_lo, wl_hi, 0..]
        bf16x8 bfrag;
        if (g == 3) {
            float x = c * weight_w[lay * EE + eN];
            ushort h = bf_hi(x);
            ushort lo = bf_hi(x - bf_f(h));
            bfrag = (bf16x8){(short)h, (short)lo, (short)h, 0, 0, 0, 0, 0};
        } else {
            const float* ewp = edge_w + lay * EDGE_F * EE + eN;
            if (g == 1) {
                #pragma unroll
                for (int m = 0; m < 8; ++m) {
                    float x = c * ewp[m * EE];
                    ushort h = bf_hi(x);
                    bfrag[m] = (short)bf_hi(x - bf_f(h));
                }
            } else {
                #pragma unroll
                for (int m = 0; m < 8; ++m)
                    bfrag[m] = (short)bf_hi(c * ewp[m * EE]);
            }
        }
        __syncthreads();   // B2: hipart ready

        const float hq = c * ((hipart[0][eN] + hipart[1][eN])
                            + (hipart[2][eN] + hipart[3][eN]));
        const f32x4 cin = {hq, hq, hq, hq};

        // ---- 32 j-tiles: MFMA + grouped-rcp tanh accumulate ----
        // per tile: 4 exp2 + 1 rcp (was 4+4); sum 1/(1+e^2x) over 4 rows:
        //   Nn/Dd = (S01*P23 + P01*S23)/(P01*P23), A_r = exp2(clamp(acc_r)) + 1
        float rsum = 0.0f;
        #pragma unroll 4
        for (int jt = 0; jt < 32; ++jt) {
            bf16x8 a = afr[jt * 64 + l];
            f32x4 acc = __builtin_amdgcn_mfma_f32_16x16x32_bf16(a, bfrag, cin, 0, 0, 0);
            float A0 = __builtin_amdgcn_exp2f(fminf(acc[0], 30.0f)) + 1.0f;
            float A1 = __builtin_amdgcn_exp2f(fminf(acc[1], 30.0f)) + 1.0f;
            float A2 = __builtin_amdgcn_exp2f(fminf(acc[2], 30.0f)) + 1.0f;
            float A3 = __builtin_amdgcn_exp2f(fminf(acc[3], 30.0f)) + 1.0f;
            float P01 = A0 * A1, S01 = A0 + A1;
            float P23 = A2 * A3, S23 = A2 + A3;
            float Nn = fmaf(P01, S23, S01 * P23);
            float Dd = P01 * P23;            // <= 2^120, finite
            rsum = fmaf(Nn, __builtin_amdgcn_rcpf(Dd), rsum);
        }
        float s = rsum;
        s += __shfl_xor(s, 16);
        s += __shfl_xor(s, 32);
        if (l < 16)
            aggfin[w * 16 + le] = 1.0f - s * (1.0f / 256.0f);
        __syncthreads();   // B3: aggfin ready

        // ---- out partial: all 512 threads, k in [ks*32, ks*32+32) ----
        {
            const float* ow = out_w + lay * EE * EE + ks * 32 * EE + e;
            float op = 0.0f;
            #pragma unroll 8
            for (int k = 0; k < 32; ++k)
                op = fmaf(aggfin[ks * 32 + k], ow[k * EE], op);
            opart[ks][e] = op;
        }
        __syncthreads();   // B4: opart ready

        if (t < EE) {
            hsh[t] = hsh[t] + out_b[lay * EE + t]
                   + (opart[0][t] + opart[1][t]) + (opart[2][t] + opart[3][t]);
        }
        // next B1 protects the hsh update
    }

    __syncthreads();
    if (t < EE) hout[(size_t)row * EE + t] = hsh[t];
}

__global__ __launch_bounds__(1024) void k_tail(
    const float* __restrict__ hbuf,        // B*N,128
    const int*   __restrict__ open_group,  // B,N
    const float* __restrict__ context_w,   // 128,128
    const float* __restrict__ key_w,       // 128,128
    const int*   __restrict__ action_mask, // B,N
    const float* __restrict__ logit_bias,  // 1
    float* __restrict__ out)               // B,N
{
    const int b = blockIdx.x;
    const int t = threadIdx.x;
    const int e = t & 127;
    const int s = t >> 7;                  // 0..7

    __shared__ float gmsh[8][EE];
    __shared__ float cntsh[8];
    __shared__ float csh[EE];
    __shared__ float qsh[EE];
    __shared__ float qksh[EE];

    const float* hb = hbuf + (size_t)b * NN * EE;

    // masked group-sum over n, 8-way split
    float gm = 0.0f, cnt = 0.0f;
    const int n0 = s * 64;
    #pragma unroll 4
    for (int u = 0; u < 64; ++u) {
        const int n = n0 + u;
        const float m = (float)open_group[b * NN + n];
        gm = fmaf(m, hb[(size_t)n * EE + e], gm);
        cnt += m;
    }
    gmsh[s][e] = gm;
    if (e == 0) cntsh[s] = cnt;
    __syncthreads();

    if (s == 0) {
        float ca = 0.0f, ga = 0.0f;
        #pragma unroll
        for (int u = 0; u < 8; ++u) { ca += cntsh[u]; ga += gmsh[u][e]; }
        csh[e] = (ca > 0.0f) ? (ga / fmaxf(ca, 1.0f)) : hb[e];  // hb[e]=h[b,0,e]
    }
    __syncthreads();

    if (s == 0) {
        float q = 0.0f;
        #pragma unroll 8
        for (int k = 0; k < EE; ++k)
            q = fmaf(csh[k], context_w[k * EE + e], q);
        qsh[e] = q;
    }
    __syncthreads();

    if (s == 0) {
        float acc = 0.0f;
        const float* kr = key_w + e * EE;   // qk[e] = key_w[e,:] . q
        #pragma unroll 8
        for (int k = 0; k < EE; ++k)
            acc = fmaf(kr[k], qsh[k], acc);
        qksh[e] = acc;
    }
    __syncthreads();

    // ---- logits: 16 waves x 32 rows each ----
    const int wid  = t >> 6;               // 0..15
    const int lane = t & 63;
    const float lb = logit_bias[0];

    for (int r = wid; r < NN; r += 16) {
        const float* hr = hb + (size_t)r * EE;
        float p = hr[lane] * qksh[lane] + hr[lane + 64] * qksh[lane + 64];
        #pragma unroll
        for (int off = 32; off; off >>= 1)
            p += __shfl_down(p, off);
        if (lane == 0) {
            float v = fmaf(p, 0.08838834764831845f, lb);   // /sqrt(128)
            out[b * NN + r] = action_mask[b * NN + r] ? v : -1000000000.0f;
        }
    }
}

extern "C" void kernel_launch(void* const* d_in, const int* in_sizes, int n_in,
                              void* d_out, int out_size, void* d_ws, size_t ws_size,
                              hipStream_t stream) {
    const float* nf         = (const float*)d_in[0];
    const float* ef         = (const float*)d_in[1];
    const float* W          = (const float*)d_in[2];
    const int*   assigned   = (const int*)d_in[3];
    const int*   open_group = (const int*)d_in[4];
    const int*   action_mask= (const int*)d_in[5];
    const float* build_limit= (const float*)d_in[6];
    const float* og_size    = (const float*)d_in[7];
    const float* embed_w    = (const float*)d_in[8];
    const float* embed_b    = (const float*)d_in[9];
    const float* node_w     = (const float*)d_in[10];
    const float* edge_w     = (const float*)d_in[11];
    const float* weight_w   = (const float*)d_in[12];
    const float* out_w      = (const float*)d_in[13];
    const float* out_b      = (const float*)d_in[14];
    const float* context_w  = (const float*)d_in[15];
    const float* key_w      = (const float*)d_in[16];
    const float* logit_bias = (const float*)d_in[17];

    float* hbuf = (float*)d_ws;                       // B*N*E floats = 1 MB

    dim3 grid_rows(NN, BB, 1);
    k_rows<<<grid_rows, 512, 0, stream>>>(nf, ef, W, assigned, open_group,
        action_mask, build_limit, og_size, embed_w, embed_b, node_w, edge_w,
        weight_w, out_w, out_b, hbuf);

    k_tail<<<BB, 1024, 0, stream>>>(hbuf, open_group, context_w, key_w,
        action_mask, logit_bias, (float*)d_out);
}

// Round 9
// 231.731 us; speedup vs baseline: 1.0736x; 1.0736x over previous
//
#include <hip/hip_runtime.h>
#include <math.h>

#define BB 4
#define NN 512
#define EE 128
#define NODE_F 16
#define EDGE_F 8
#define LL 3

typedef __attribute__((ext_vector_type(8))) short bf16x8;
typedef __attribute__((ext_vector_type(4))) float f32x4;

__device__ __forceinline__ ushort bf_hi(float x) {
    uint u = __float_as_uint(x);
    return (ushort)((u + 0x7fffu + ((u >> 16) & 1u)) >> 16);
}
__device__ __forceinline__ float bf_f(ushort h) {
    return __uint_as_float(((uint)h) << 16);
}

__global__ __launch_bounds__(512) void k_rows(
    const float* __restrict__ nf,          // B,N,16
    const float* __restrict__ ef,          // B,N,N,8
    const float* __restrict__ W,           // B,N,N
    const int*   __restrict__ assigned,    // B,N
    const int*   __restrict__ open_group,  // B,N
    const int*   __restrict__ action_mask, // B,N
    const float* __restrict__ build_limit, // B,3
    const float* __restrict__ open_group_size, // B,3
    const float* __restrict__ embed_w,     // 22,128
    const float* __restrict__ embed_b,     // 128
    const float* __restrict__ node_w,      // L,128,128
    const float* __restrict__ edge_w,      // L,8,128
    const float* __restrict__ weight_w,    // L,128
    const float* __restrict__ out_w,       // L,128,128
    const float* __restrict__ out_b,       // L,128
    float* __restrict__ hout)              // B*N,128
{
    const int i   = blockIdx.x;
    const int b   = blockIdx.y;
    const int t   = threadIdx.x;
    const int l   = t & 63;                // lane
    const int w   = t >> 6;                // wave 0..7 -> e-tile
    const int e   = t & 127;               // for split-k dots
    const int ks  = t >> 7;                // 0..3, k-slot for dots
    const int row = b * NN + i;

    // A-fragments: [32 j-tiles][64 lanes] x 8 bf16 = 32 KB
    __shared__ bf16x8 afr[32 * 64];
    __shared__ float hsh[EE];
    __shared__ float hipart[4][EE];
    __shared__ float opart[4][EE];
    __shared__ float aggfin[EE];
    __shared__ float xsh[24];

    // ---- x = [node_features(16), assigned, open, mask, ratio(3)] ----
    if (t < NODE_F) {
        xsh[t] = nf[row * NODE_F + t];
    } else if (t == 16) {
        xsh[16] = assigned[row] ? 1.0f : 0.0f;
    } else if (t == 17) {
        xsh[17] = open_group[row] ? 1.0f : 0.0f;
    } else if (t == 18) {
        xsh[18] = action_mask[row] ? 1.0f : 0.0f;
    } else if (t < 22) {
        int k = t - 19;
        xsh[t] = open_group_size[b * 3 + k] / fmaxf(build_limit[b * 3 + k], 1e-6f);
    }

    // ---- pack A-fragments (once; layer-invariant) ----
    // K slots: 0-7: ef_hi  8-15: ef_hi  16-23: ef_lo  24: W_hi 25: W_hi 26: W_lo
    // lane ll of tile jt holds A[j = jt*16 + (ll&15), k = (ll>>4)*8 .. +8]
    {
        const float* efr = ef + (size_t)row * NN * EDGE_F;
        const float* Wr  = W + (size_t)row * NN;
        #pragma unroll
        for (int q = 0; q < 4; ++q) {
            const int eid = t + 512 * q;        // 0..2047
            const int ll  = eid & 63;
            const int jt  = eid >> 6;
            const int g   = ll >> 4;
            const int jj  = jt * 16 + (ll & 15);
            bf16x8 frag;
            if (g < 3) {
                const float4 a = *(const float4*)&efr[jj * 8];
                const float4 c4 = *(const float4*)&efr[jj * 8 + 4];
                float v[8] = {a.x, a.y, a.z, a.w, c4.x, c4.y, c4.z, c4.w};
                if (g < 2) {
                    #pragma unroll
                    for (int m = 0; m < 8; ++m) frag[m] = (short)bf_hi(v[m]);
                } else {
                    #pragma unroll
                    for (int m = 0; m < 8; ++m) {
                        ushort h = bf_hi(v[m]);
                        frag[m] = (short)bf_hi(v[m] - bf_f(h));
                    }
                }
            } else {
                float wv = Wr[jj];
                ushort h = bf_hi(wv);
                ushort lo = bf_hi(wv - bf_f(h));
                frag = (bf16x8){(short)h, (short)h, (short)lo, 0, 0, 0, 0, 0};
            }
            afr[eid] = frag;
        }
    }
    __syncthreads();

    // ---- h0 = x @ embed_w + embed_b ----
    if (t < EE) {
        float h0 = embed_b[t];
        #pragma unroll
        for (int k = 0; k < 22; ++k)
            h0 = fmaf(xsh[k], embed_w[k * EE + t], h0);
        hsh[t] = h0;
    }

    const float c  = 2.8853900817779268f;  // 2*log2(e) folded into weights
    const int  le  = l & 15;
    const int  g   = l >> 4;
    const int  eN  = w * 16 + le;          // this lane's e column

    for (int lay = 0; lay < LL; ++lay) {
        __syncthreads();   // B1: hsh stable, previous layer's LDS reads done

        // ---- hi partial: all 512 threads, k in [ks*32,+32), 16-wide prefetch ----
        {
            const float* nw = node_w + lay * EE * EE + ks * 32 * EE + e;
            float hp = 0.0f;
            #pragma unroll
            for (int kk = 0; kk < 2; ++kk) {
                float wreg[16];
                #pragma unroll
                for (int k2 = 0; k2 < 16; ++k2)
                    wreg[k2] = nw[(kk * 16 + k2) * EE];
                #pragma unroll
                for (int k2 = 0; k2 < 16; ++k2)
                    hp = fmaf(hsh[ks * 32 + kk * 16 + k2], wreg[k2], hp);
            }
            hipart[ks][e] = hp;
        }

        // ---- B-fragment for this lane (fixed per layer) ----
        // B[k = g*8+m, n = le]:  g0: we_hi  g1: we_lo  g2: we_hi  g3: [wl_hi, wl_lo, wl_hi, 0..]
        bf16x8 bfrag;
        if (g == 3) {
            float x = c * weight_w[lay * EE + eN];
            ushort h = bf_hi(x);
            ushort lo = bf_hi(x - bf_f(h));
            bfrag = (bf16x8){(short)h, (short)lo, (short)h, 0, 0, 0, 0, 0};
        } else {
            const float* ewp = edge_w + lay * EDGE_F * EE + eN;
            if (g == 1) {
                #pragma unroll
                for (int m = 0; m < 8; ++m) {
                    float x = c * ewp[m * EE];
                    ushort h = bf_hi(x);
                    bfrag[m] = (short)bf_hi(x - bf_f(h));
                }
            } else {
                #pragma unroll
                for (int m = 0; m < 8; ++m)
                    bfrag[m] = (short)bf_hi(c * ewp[m * EE]);
            }
        }
        __syncthreads();   // B2: hipart ready

        const float hq = c * ((hipart[0][eN] + hipart[1][eN])
                            + (hipart[2][eN] + hipart[3][eN]));
        const f32x4 cin = {hq, hq, hq, hq};

        // ---- 32 j-tiles: MFMA + simple tanh accumulate (R6 form) ----
        // graceful overflow: exp2(big)=inf -> rcp(inf)=0, never NaN
        f32x4 rsum = {0.0f, 0.0f, 0.0f, 0.0f};
        #pragma unroll 4
        for (int jt = 0; jt < 32; ++jt) {
            bf16x8 a = afr[jt * 64 + l];
            f32x4 acc = __builtin_amdgcn_mfma_f32_16x16x32_bf16(a, bfrag, cin, 0, 0, 0);
            #pragma unroll
            for (int r = 0; r < 4; ++r) {
                float ex = __builtin_amdgcn_exp2f(acc[r]);
                rsum[r] += __builtin_amdgcn_rcpf(ex + 1.0f);
            }
        }
        float s = (rsum[0] + rsum[1]) + (rsum[2] + rsum[3]);
        s += __shfl_xor(s, 16);
        s += __shfl_xor(s, 32);
        if (l < 16)
            aggfin[w * 16 + le] = 1.0f - s * (1.0f / 256.0f);
        __syncthreads();   // B3: aggfin ready

        // ---- out partial: all 512 threads, k in [ks*32,+32), 16-wide prefetch ----
        {
            const float* ow = out_w + lay * EE * EE + ks * 32 * EE + e;
            float op = 0.0f;
            #pragma unroll
            for (int kk = 0; kk < 2; ++kk) {
                float wreg[16];
                #pragma unroll
                for (int k2 = 0; k2 < 16; ++k2)
                    wreg[k2] = ow[(kk * 16 + k2) * EE];
                #pragma unroll
                for (int k2 = 0; k2 < 16; ++k2)
                    op = fmaf(aggfin[ks * 32 + kk * 16 + k2], wreg[k2], op);
            }
            opart[ks][e] = op;
        }
        __syncthreads();   // B4: opart ready

        if (t < EE) {
            hsh[t] = hsh[t] + out_b[lay * EE + t]
                   + (opart[0][t] + opart[1][t]) + (opart[2][t] + opart[3][t]);
        }
        // next B1 protects the hsh update
    }

    __syncthreads();
    if (t < EE) hout[(size_t)row * EE + t] = hsh[t];
}

__global__ __launch_bounds__(1024) void k_ctx(
    const float* __restrict__ hbuf,        // B*N,128
    const int*   __restrict__ open_group,  // B,N
    const float* __restrict__ context_w,   // 128,128
    const float* __restrict__ key_w,       // 128,128
    float* __restrict__ qk)                // B,128
{
    const int b = blockIdx.x;
    const int t = threadIdx.x;
    const int e = t & 127;
    const int s = t >> 7;                  // 0..7

    __shared__ float gmsh[8][EE];
    __shared__ float cntsh[8];
    __shared__ float csh[EE];
    __shared__ float qsh[EE];

    const float* hb = hbuf + (size_t)b * NN * EE;

    // masked group-sum over n, 8-way split
    float gm = 0.0f, cnt = 0.0f;
    const int n0 = s * 64;
    #pragma unroll 8
    for (int u = 0; u < 64; ++u) {
        const int n = n0 + u;
        const float m = (float)open_group[b * NN + n];
        gm = fmaf(m, hb[(size_t)n * EE + e], gm);
        cnt += m;
    }
    gmsh[s][e] = gm;
    if (e == 0) cntsh[s] = cnt;
    __syncthreads();

    if (s == 0) {
        float ca = 0.0f, ga = 0.0f;
        #pragma unroll
        for (int u = 0; u < 8; ++u) { ca += cntsh[u]; ga += gmsh[u][e]; }
        csh[e] = (ca > 0.0f) ? (ga / fmaxf(ca, 1.0f)) : hb[e];  // hb[e]=h[b,0,e]
    }
    __syncthreads();

    if (s == 0) {
        float q = 0.0f;
        #pragma unroll
        for (int kk = 0; kk < 8; ++kk) {
            float wreg[16];
            #pragma unroll
            for (int k2 = 0; k2 < 16; ++k2)
                wreg[k2] = context_w[(kk * 16 + k2) * EE + e];
            #pragma unroll
            for (int k2 = 0; k2 < 16; ++k2)
                q = fmaf(csh[kk * 16 + k2], wreg[k2], q);
        }
        qsh[e] = q;
    }
    __syncthreads();

    if (s == 0) {
        float acc = 0.0f;
        const float* kr = key_w + e * EE;   // qk[e] = key_w[e,:] . q
        #pragma unroll
        for (int kk = 0; kk < 8; ++kk) {
            float wreg[16];
            #pragma unroll
            for (int k2 = 0; k2 < 16; ++k2)
                wreg[k2] = kr[kk * 16 + k2];
            #pragma unroll
            for (int k2 = 0; k2 < 16; ++k2)
                acc = fmaf(wreg[k2], qsh[kk * 16 + k2], acc);
        }
        qk[b * EE + e] = acc;
    }
}

__global__ __launch_bounds__(512) void k_logits(
    const float* __restrict__ hbuf,        // B*N,128
    const float* __restrict__ qk,          // B,128
    const int*   __restrict__ action_mask, // B,N
    const float* __restrict__ logit_bias,  // 1
    float* __restrict__ out)               // B,N
{
    const int b    = blockIdx.y;
    const int base = blockIdx.x * 32;      // 16 blocks cover 512 rows
    const int wid  = threadIdx.x >> 6;     // 0..7
    const int lane = threadIdx.x & 63;

    const float* hb = hbuf + (size_t)b * NN * EE;
    const float* qb = qk + b * EE;
    const float q0 = qb[lane];
    const float q1 = qb[lane + 64];
    const float lb = logit_bias[0];

    #pragma unroll
    for (int u = 0; u < 4; ++u) {
        const int r = base + wid * 4 + u;
        const float* hr = hb + (size_t)r * EE;
        float p = hr[lane] * q0 + hr[lane + 64] * q1;
        #pragma unroll
        for (int off = 32; off; off >>= 1)
            p += __shfl_down(p, off);
        if (lane == 0) {
            float v = fmaf(p, 0.08838834764831845f, lb);   // /sqrt(128)
            out[b * NN + r] = action_mask[b * NN + r] ? v : -1000000000.0f;
        }
    }
}

extern "C" void kernel_launch(void* const* d_in, const int* in_sizes, int n_in,
                              void* d_out, int out_size, void* d_ws, size_t ws_size,
                              hipStream_t stream) {
    const float* nf         = (const float*)d_in[0];
    const float* ef         = (const float*)d_in[1];
    const float* W          = (const float*)d_in[2];
    const int*   assigned   = (const int*)d_in[3];
    const int*   open_group = (const int*)d_in[4];
    const int*   action_mask= (const int*)d_in[5];
    const float* build_limit= (const float*)d_in[6];
    const float* og_size    = (const float*)d_in[7];
    const float* embed_w    = (const float*)d_in[8];
    const float* embed_b    = (const float*)d_in[9];
    const float* node_w     = (const float*)d_in[10];
    const float* edge_w     = (const float*)d_in[11];
    const float* weight_w   = (const float*)d_in[12];
    const float* out_w      = (const float*)d_in[13];
    const float* out_b      = (const float*)d_in[14];
    const float* context_w  = (const float*)d_in[15];
    const float* key_w      = (const float*)d_in[16];
    const float* logit_bias = (const float*)d_in[17];

    float* hbuf = (float*)d_ws;                       // B*N*E floats = 1 MB
    float* qk   = hbuf + (size_t)BB * NN * EE;        // B*E floats

    dim3 grid_rows(NN, BB, 1);
    k_rows<<<grid_rows, 512, 0, stream>>>(nf, ef, W, assigned, open_group,
        action_mask, build_limit, og_size, embed_w, embed_b, node_w, edge_w,
        weight_w, out_w, out_b, hbuf);

    k_ctx<<<BB, 1024, 0, stream>>>(hbuf, open_group, context_w, key_w, qk);

    dim3 grid_log(16, BB, 1);
    k_logits<<<grid_log, 512, 0, stream>>>(hbuf, qk, action_mask, logit_bias,
        (float*)d_out);
}

// Round 10
// 220.933 us; speedup vs baseline: 1.1261x; 1.0489x over previous
//
#include <hip/hip_runtime.h>
#include <math.h>

#define BB 4
#define NN 512
#define EE 128
#define NODE_F 16
#define EDGE_F 8
#define LL 3

typedef __attribute__((ext_vector_type(8))) short bf16x8;
typedef __attribute__((ext_vector_type(4))) float f32x4;

__device__ __forceinline__ ushort bf_hi(float x) {
    uint u = __float_as_uint(x);
    return (ushort)((u + 0x7fffu + ((u >> 16) & 1u)) >> 16);
}
__device__ __forceinline__ float bf_f(ushort h) {
    return __uint_as_float(((uint)h) << 16);
}

__global__ __launch_bounds__(512) void k_zero(float* __restrict__ gbuf) {
    // zero gsum[BB][EE] + gcnt[BB]
    for (int i = threadIdx.x; i < BB * EE + BB; i += 512)
        gbuf[i] = 0.0f;
}

__global__ __launch_bounds__(512) void k_rows(
    const float* __restrict__ nf,          // B,N,16
    const float* __restrict__ ef,          // B,N,N,8
    const float* __restrict__ W,           // B,N,N
    const int*   __restrict__ assigned,    // B,N
    const int*   __restrict__ open_group,  // B,N
    const int*   __restrict__ action_mask, // B,N
    const float* __restrict__ build_limit, // B,3
    const float* __restrict__ open_group_size, // B,3
    const float* __restrict__ embed_w,     // 22,128
    const float* __restrict__ embed_b,     // 128
    const float* __restrict__ node_w,      // L,128,128
    const float* __restrict__ edge_w,      // L,8,128
    const float* __restrict__ weight_w,    // L,128
    const float* __restrict__ out_w,       // L,128,128
    const float* __restrict__ out_b,       // L,128
    float* __restrict__ hout,              // B*N,128
    float* __restrict__ gsum,              // B,128 (atomic)
    float* __restrict__ gcnt)              // B (atomic)
{
    const int i   = blockIdx.x;
    const int b   = blockIdx.y;
    const int t   = threadIdx.x;
    const int l   = t & 63;                // lane
    const int w   = t >> 6;                // wave 0..7 -> e-tile
    const int row = b * NN + i;

    // A-fragments: [32 j-tiles][64 lanes] x 8 bf16 = 32 KB
    __shared__ bf16x8 afr[32 * 64];
    __shared__ float hsh[EE];
    __shared__ float aggfin[EE];
    __shared__ float xsh[24];

    // ---- x = [node_features(16), assigned, open, mask, ratio(3)] ----
    if (t < NODE_F) {
        xsh[t] = nf[row * NODE_F + t];
    } else if (t == 16) {
        xsh[16] = assigned[row] ? 1.0f : 0.0f;
    } else if (t == 17) {
        xsh[17] = open_group[row] ? 1.0f : 0.0f;
    } else if (t == 18) {
        xsh[18] = action_mask[row] ? 1.0f : 0.0f;
    } else if (t < 22) {
        int k = t - 19;
        xsh[t] = open_group_size[b * 3 + k] / fmaxf(build_limit[b * 3 + k], 1e-6f);
    }

    // ---- pack A-fragments (once; layer-invariant) ----
    // K slots: 0-7: ef_hi  8-15: ef_hi  16-23: ef_lo  24: W_hi 25: W_hi 26: W_lo
    // lane ll of tile jt holds A[j = jt*16 + (ll&15), k = (ll>>4)*8 .. +8]
    {
        const float* efr = ef + (size_t)row * NN * EDGE_F;
        const float* Wr  = W + (size_t)row * NN;
        #pragma unroll
        for (int q = 0; q < 4; ++q) {
            const int eid = t + 512 * q;        // 0..2047
            const int ll  = eid & 63;
            const int jt  = eid >> 6;
            const int g   = ll >> 4;
            const int jj  = jt * 16 + (ll & 15);
            bf16x8 frag;
            if (g < 3) {
                const float4 a = *(const float4*)&efr[jj * 8];
                const float4 c4 = *(const float4*)&efr[jj * 8 + 4];
                float v[8] = {a.x, a.y, a.z, a.w, c4.x, c4.y, c4.z, c4.w};
                if (g < 2) {
                    #pragma unroll
                    for (int m = 0; m < 8; ++m) frag[m] = (short)bf_hi(v[m]);
                } else {
                    #pragma unroll
                    for (int m = 0; m < 8; ++m) {
                        ushort h = bf_hi(v[m]);
                        frag[m] = (short)bf_hi(v[m] - bf_f(h));
                    }
                }
            } else {
                float wv = Wr[jj];
                ushort h = bf_hi(wv);
                ushort lo = bf_hi(wv - bf_f(h));
                frag = (bf16x8){(short)h, (short)h, (short)lo, 0, 0, 0, 0, 0};
            }
            afr[eid] = frag;
        }
    }
    __syncthreads();

    // ---- h0 = x @ embed_w + embed_b ----
    if (t < EE) {
        float h0 = embed_b[t];
        #pragma unroll
        for (int k = 0; k < 22; ++k)
            h0 = fmaf(xsh[k], embed_w[k * EE + t], h0);
        hsh[t] = h0;
    }

    const float c  = 2.8853900817779268f;  // 2*log2(e) folded into weights
    const int  le  = l & 15;
    const int  g   = l >> 4;               // k-quarter for in-wave dots
    const int  eN  = w * 16 + le;          // this lane's e column

    for (int lay = 0; lay < LL; ++lay) {
        __syncthreads();   // B1: hsh stable for all waves

        // ---- hi[eN]: in-wave dot; lane handles k in [g*32, g*32+32) ----
        float hp = 0.0f;
        {
            const float* nw = node_w + lay * EE * EE + g * 32 * EE + eN;
            #pragma unroll
            for (int kk = 0; kk < 2; ++kk) {
                float wreg[16];
                #pragma unroll
                for (int k2 = 0; k2 < 16; ++k2)
                    wreg[k2] = nw[(kk * 16 + k2) * EE];
                #pragma unroll
                for (int k2 = 0; k2 < 16; ++k2)
                    hp = fmaf(hsh[g * 32 + kk * 16 + k2], wreg[k2], hp);
            }
            hp += __shfl_xor(hp, 16);
            hp += __shfl_xor(hp, 32);      // all lanes: full hi for their le
        }
        const float hq = c * hp;

        // ---- B-fragment for this lane (fixed per layer) ----
        // B[k = g*8+m, n = le]:  g0: we_hi  g1: we_lo  g2: we_hi  g3: [wl_hi, wl_lo, wl_hi, 0..]
        bf16x8 bfrag;
        if (g == 3) {
            float x = c * weight_w[lay * EE + eN];
            ushort h = bf_hi(x);
            ushort lo = bf_hi(x - bf_f(h));
            bfrag = (bf16x8){(short)h, (short)lo, (short)h, 0, 0, 0, 0, 0};
        } else {
            const float* ewp = edge_w + lay * EDGE_F * EE + eN;
            if (g == 1) {
                #pragma unroll
                for (int m = 0; m < 8; ++m) {
                    float x = c * ewp[m * EE];
                    ushort h = bf_hi(x);
                    bfrag[m] = (short)bf_hi(x - bf_f(h));
                }
            } else {
                #pragma unroll
                for (int m = 0; m < 8; ++m)
                    bfrag[m] = (short)bf_hi(c * ewp[m * EE]);
            }
        }

        const f32x4 cin = {hq, hq, hq, hq};

        // ---- 32 j-tiles: MFMA + simple tanh accumulate ----
        // graceful overflow: exp2(big)=inf -> rcp(inf)=0, never NaN
        f32x4 rsum = {0.0f, 0.0f, 0.0f, 0.0f};
        #pragma unroll 4
        for (int jt = 0; jt < 32; ++jt) {
            bf16x8 a = afr[jt * 64 + l];
            f32x4 acc = __builtin_amdgcn_mfma_f32_16x16x32_bf16(a, bfrag, cin, 0, 0, 0);
            #pragma unroll
            for (int r = 0; r < 4; ++r) {
                float ex = __builtin_amdgcn_exp2f(acc[r]);
                rsum[r] += __builtin_amdgcn_rcpf(ex + 1.0f);
            }
        }
        float s = (rsum[0] + rsum[1]) + (rsum[2] + rsum[3]);
        s += __shfl_xor(s, 16);
        s += __shfl_xor(s, 32);
        if (l < 16)
            aggfin[eN] = 1.0f - s * (1.0f / 256.0f);
        __syncthreads();   // B2: aggfin ready

        // ---- out[eN]: in-wave dot over aggfin; k in [g*32, g*32+32) ----
        float op = 0.0f;
        {
            const float* ow = out_w + lay * EE * EE + g * 32 * EE + eN;
            #pragma unroll
            for (int kk = 0; kk < 2; ++kk) {
                float wreg[16];
                #pragma unroll
                for (int k2 = 0; k2 < 16; ++k2)
                    wreg[k2] = ow[(kk * 16 + k2) * EE];
                #pragma unroll
                for (int k2 = 0; k2 < 16; ++k2)
                    op = fmaf(aggfin[g * 32 + kk * 16 + k2], wreg[k2], op);
            }
            op += __shfl_xor(op, 16);
            op += __shfl_xor(op, 32);
        }
        if (l < 16)
            hsh[eN] = hsh[eN] + out_b[lay * EE + eN] + op;
        // next B1 (or final sync) protects the hsh update
    }

    __syncthreads();
    if (t < EE) {
        const float hv = hsh[t];
        hout[(size_t)row * EE + t] = hv;
        if (open_group[row]) atomicAdd(&gsum[b * EE + t], hv);
    }
    if (t == 256 && open_group[row]) atomicAdd(&gcnt[b], 1.0f);
}

__global__ __launch_bounds__(128) void k_ctx(
    const float* __restrict__ hbuf,        // B*N,128
    const float* __restrict__ gsum,        // B,128
    const float* __restrict__ gcnt,        // B
    const float* __restrict__ context_w,   // 128,128
    const float* __restrict__ key_w,       // 128,128
    float* __restrict__ qk)                // B,128
{
    const int b = blockIdx.x;
    const int e = threadIdx.x;

    __shared__ float csh[EE];
    __shared__ float qsh[EE];

    const float cnt = gcnt[b];
    const float ctx = (cnt > 0.0f) ? (gsum[b * EE + e] / fmaxf(cnt, 1.0f))
                                   : hbuf[(size_t)b * NN * EE + e]; // h[b,0,e]
    csh[e] = ctx;
    __syncthreads();

    float q = 0.0f;
    #pragma unroll
    for (int kk = 0; kk < 8; ++kk) {
        float wreg[16];
        #pragma unroll
        for (int k2 = 0; k2 < 16; ++k2)
            wreg[k2] = context_w[(kk * 16 + k2) * EE + e];
        #pragma unroll
        for (int k2 = 0; k2 < 16; ++k2)
            q = fmaf(csh[kk * 16 + k2], wreg[k2], q);
    }
    qsh[e] = q;
    __syncthreads();

    float acc = 0.0f;
    const float* kr = key_w + e * EE;      // qk[e] = key_w[e,:] . q
    #pragma unroll
    for (int kk = 0; kk < 8; ++kk) {
        float wreg[16];
        #pragma unroll
        for (int k2 = 0; k2 < 16; ++k2)
            wreg[k2] = kr[kk * 16 + k2];
        #pragma unroll
        for (int k2 = 0; k2 < 16; ++k2)
            acc = fmaf(wreg[k2], qsh[kk * 16 + k2], acc);
    }
    qk[b * EE + e] = acc;
}

__global__ __launch_bounds__(512) void k_logits(
    const float* __restrict__ hbuf,        // B*N,128
    const float* __restrict__ qk,          // B,128
    const int*   __restrict__ action_mask, // B,N
    const float* __restrict__ logit_bias,  // 1
    float* __restrict__ out)               // B,N
{
    const int b    = blockIdx.y;
    const int base = blockIdx.x * 32;      // 16 blocks cover 512 rows
    const int wid  = threadIdx.x >> 6;     // 0..7
    const int lane = threadIdx.x & 63;

    const float* hb = hbuf + (size_t)b * NN * EE;
    const float* qb = qk + b * EE;
    const float q0 = qb[lane];
    const float q1 = qb[lane + 64];
    const float lb = logit_bias[0];

    #pragma unroll
    for (int u = 0; u < 4; ++u) {
        const int r = base + wid * 4 + u;
        const float* hr = hb + (size_t)r * EE;
        float p = hr[lane] * q0 + hr[lane + 64] * q1;
        #pragma unroll
        for (int off = 32; off; off >>= 1)
            p += __shfl_down(p, off);
        if (lane == 0) {
            float v = fmaf(p, 0.08838834764831845f, lb);   // /sqrt(128)
            out[b * NN + r] = action_mask[b * NN + r] ? v : -1000000000.0f;
        }
    }
}

extern "C" void kernel_launch(void* const* d_in, const int* in_sizes, int n_in,
                              void* d_out, int out_size, void* d_ws, size_t ws_size,
                              hipStream_t stream) {
    const float* nf         = (const float*)d_in[0];
    const float* ef         = (const float*)d_in[1];
    const float* W          = (const float*)d_in[2];
    const int*   assigned   = (const int*)d_in[3];
    const int*   open_group = (const int*)d_in[4];
    const int*   action_mask= (const int*)d_in[5];
    const float* build_limit= (const float*)d_in[6];
    const float* og_size    = (const float*)d_in[7];
    const float* embed_w    = (const float*)d_in[8];
    const float* embed_b    = (const float*)d_in[9];
    const float* node_w     = (const float*)d_in[10];
    const float* edge_w     = (const float*)d_in[11];
    const float* weight_w   = (const float*)d_in[12];
    const float* out_w      = (const float*)d_in[13];
    const float* out_b      = (const float*)d_in[14];
    const float* context_w  = (const float*)d_in[15];
    const float* key_w      = (const float*)d_in[16];
    const float* logit_bias = (const float*)d_in[17];

    float* hbuf = (float*)d_ws;                       // B*N*E floats = 1 MB
    float* qk   = hbuf + (size_t)BB * NN * EE;        // B*E
    float* gbuf = qk + BB * EE;                       // gsum B*E + gcnt B
    float* gsum = gbuf;
    float* gcnt = gbuf + BB * EE;

    k_zero<<<1, 512, 0, stream>>>(gbuf);

    dim3 grid_rows(NN, BB, 1);
    k_rows<<<grid_rows, 512, 0, stream>>>(nf, ef, W, assigned, open_group,
        action_mask, build_limit, og_size, embed_w, embed_b, node_w, edge_w,
        weight_w, out_w, out_b, hbuf, gsum, gcnt);

    k_ctx<<<BB, 128, 0, stream>>>(hbuf, gsum, gcnt, context_w, key_w, qk);

    dim3 grid_log(16, BB, 1);
    k_logits<<<grid_log, 512, 0, stream>>>(hbuf, qk, action_mask, logit_bias,
        (float*)d_out);
}

// Round 11
// 218.892 us; speedup vs baseline: 1.1366x; 1.0093x over previous
//
#include <hip/hip_runtime.h>
#include <math.h>

#define BB 4
#define NN 512
#define EE 128
#define NODE_F 16
#define EDGE_F 8
#define LL 3

typedef __attribute__((ext_vector_type(8))) short bf16x8;
typedef __attribute__((ext_vector_type(4))) float f32x4;

__device__ __forceinline__ ushort bf_hi(float x) {
    uint u = __float_as_uint(x);
    return (ushort)((u + 0x7fffu + ((u >> 16) & 1u)) >> 16);
}
__device__ __forceinline__ float bf_f(ushort h) {
    return __uint_as_float(((uint)h) << 16);
}

__global__ __launch_bounds__(512) void k_rows(
    const float* __restrict__ nf,          // B,N,16
    const float* __restrict__ ef,          // B,N,N,8
    const float* __restrict__ W,           // B,N,N
    const int*   __restrict__ assigned,    // B,N
    const int*   __restrict__ open_group,  // B,N
    const int*   __restrict__ action_mask, // B,N
    const float* __restrict__ build_limit, // B,3
    const float* __restrict__ open_group_size, // B,3
    const float* __restrict__ embed_w,     // 22,128
    const float* __restrict__ embed_b,     // 128
    const float* __restrict__ node_w,      // L,128,128
    const float* __restrict__ edge_w,      // L,8,128
    const float* __restrict__ weight_w,    // L,128
    const float* __restrict__ out_w,       // L,128,128
    const float* __restrict__ out_b,       // L,128
    float* __restrict__ hout)              // B*N,128
{
    const int i   = blockIdx.x;
    const int b   = blockIdx.y;
    const int t   = threadIdx.x;
    const int l   = t & 63;                // lane
    const int w   = t >> 6;                // wave 0..7 -> e-tile
    const int row = b * NN + i;

    // A-fragments: [32 j-tiles][64 lanes] x 8 bf16 = 32 KB
    __shared__ bf16x8 afr[32 * 64];
    __shared__ float hsh[EE];
    __shared__ float aggfin[EE];
    __shared__ float xsh[24];

    // ---- x = [node_features(16), assigned, open, mask, ratio(3)] ----
    if (t < NODE_F) {
        xsh[t] = nf[row * NODE_F + t];
    } else if (t == 16) {
        xsh[16] = assigned[row] ? 1.0f : 0.0f;
    } else if (t == 17) {
        xsh[17] = open_group[row] ? 1.0f : 0.0f;
    } else if (t == 18) {
        xsh[18] = action_mask[row] ? 1.0f : 0.0f;
    } else if (t < 22) {
        int k = t - 19;
        xsh[t] = open_group_size[b * 3 + k] / fmaxf(build_limit[b * 3 + k], 1e-6f);
    }

    // ---- pack A-fragments (once; layer-invariant) ----
    // K slots: 0-7: ef_hi  8-15: ef_hi  16-23: ef_lo  24: W_hi 25: W_hi 26: W_lo
    // lane ll of tile jt holds A[j = jt*16 + (ll&15), k = (ll>>4)*8 .. +8]
    {
        const float* efr = ef + (size_t)row * NN * EDGE_F;
        const float* Wr  = W + (size_t)row * NN;
        #pragma unroll
        for (int q = 0; q < 4; ++q) {
            const int eid = t + 512 * q;        // 0..2047
            const int ll  = eid & 63;
            const int jt  = eid >> 6;
            const int g   = ll >> 4;
            const int jj  = jt * 16 + (ll & 15);
            bf16x8 frag;
            if (g < 3) {
                const float4 a = *(const float4*)&efr[jj * 8];
                const float4 c4 = *(const float4*)&efr[jj * 8 + 4];
                float v[8] = {a.x, a.y, a.z, a.w, c4.x, c4.y, c4.z, c4.w};
                if (g < 2) {
                    #pragma unroll
                    for (int m = 0; m < 8; ++m) frag[m] = (short)bf_hi(v[m]);
                } else {
                    #pragma unroll
                    for (int m = 0; m < 8; ++m) {
                        ushort h = bf_hi(v[m]);
                        frag[m] = (short)bf_hi(v[m] - bf_f(h));
                    }
                }
            } else {
                float wv = Wr[jj];
                ushort h = bf_hi(wv);
                ushort lo = bf_hi(wv - bf_f(h));
                frag = (bf16x8){(short)h, (short)h, (short)lo, 0, 0, 0, 0, 0};
            }
            afr[eid] = frag;
        }
    }
    __syncthreads();

    // ---- h0 = x @ embed_w + embed_b ----
    if (t < EE) {
        float h0 = embed_b[t];
        #pragma unroll
        for (int k = 0; k < 22; ++k)
            h0 = fmaf(xsh[k], embed_w[k * EE + t], h0);
        hsh[t] = h0;
    }

    const float c  = 2.8853900817779268f;  // 2*log2(e) folded into weights
    const int  le  = l & 15;
    const int  g   = l >> 4;               // k-quarter for in-wave dots
    const int  eN  = w * 16 + le;          // this lane's e column

    for (int lay = 0; lay < LL; ++lay) {
        __syncthreads();   // B1: hsh stable for all waves

        // ---- hi[eN]: in-wave dot; lane handles k in [g*32, g*32+32) ----
        float hp = 0.0f;
        {
            const float* nw = node_w + lay * EE * EE + g * 32 * EE + eN;
            #pragma unroll
            for (int kk = 0; kk < 2; ++kk) {
                float wreg[16];
                #pragma unroll
                for (int k2 = 0; k2 < 16; ++k2)
                    wreg[k2] = nw[(kk * 16 + k2) * EE];
                #pragma unroll
                for (int k2 = 0; k2 < 16; ++k2)
                    hp = fmaf(hsh[g * 32 + kk * 16 + k2], wreg[k2], hp);
            }
            hp += __shfl_xor(hp, 16);
            hp += __shfl_xor(hp, 32);      // all lanes: full hi for their le
        }
        const float hq = c * hp;

        // ---- B-fragment for this lane (fixed per layer) ----
        // B[k = g*8+m, n = le]:  g0: we_hi  g1: we_lo  g2: we_hi  g3: [wl_hi, wl_lo, wl_hi, 0..]
        bf16x8 bfrag;
        if (g == 3) {
            float x = c * weight_w[lay * EE + eN];
            ushort h = bf_hi(x);
            ushort lo = bf_hi(x - bf_f(h));
            bfrag = (bf16x8){(short)h, (short)lo, (short)h, 0, 0, 0, 0, 0};
        } else {
            const float* ewp = edge_w + lay * EDGE_F * EE + eN;
            if (g == 1) {
                #pragma unroll
                for (int m = 0; m < 8; ++m) {
                    float x = c * ewp[m * EE];
                    ushort h = bf_hi(x);
                    bfrag[m] = (short)bf_hi(x - bf_f(h));
                }
            } else {
                #pragma unroll
                for (int m = 0; m < 8; ++m)
                    bfrag[m] = (short)bf_hi(c * ewp[m * EE]);
            }
        }

        const f32x4 cin = {hq, hq, hq, hq};

        // ---- 32 j-tiles: MFMA + simple tanh accumulate ----
        // graceful overflow: exp2(big)=inf -> rcp(inf)=0, never NaN
        f32x4 rsum = {0.0f, 0.0f, 0.0f, 0.0f};
        #pragma unroll 4
        for (int jt = 0; jt < 32; ++jt) {
            bf16x8 a = afr[jt * 64 + l];
            f32x4 acc = __builtin_amdgcn_mfma_f32_16x16x32_bf16(a, bfrag, cin, 0, 0, 0);
            #pragma unroll
            for (int r = 0; r < 4; ++r) {
                float ex = __builtin_amdgcn_exp2f(acc[r]);
                rsum[r] += __builtin_amdgcn_rcpf(ex + 1.0f);
            }
        }
        float s = (rsum[0] + rsum[1]) + (rsum[2] + rsum[3]);
        s += __shfl_xor(s, 16);
        s += __shfl_xor(s, 32);
        if (l < 16)
            aggfin[eN] = 1.0f - s * (1.0f / 256.0f);
        __syncthreads();   // B2: aggfin ready

        // ---- out[eN]: in-wave dot over aggfin; k in [g*32, g*32+32) ----
        float op = 0.0f;
        {
            const float* ow = out_w + lay * EE * EE + g * 32 * EE + eN;
            #pragma unroll
            for (int kk = 0; kk < 2; ++kk) {
                float wreg[16];
                #pragma unroll
                for (int k2 = 0; k2 < 16; ++k2)
                    wreg[k2] = ow[(kk * 16 + k2) * EE];
                #pragma unroll
                for (int k2 = 0; k2 < 16; ++k2)
                    op = fmaf(aggfin[g * 32 + kk * 16 + k2], wreg[k2], op);
            }
            op += __shfl_xor(op, 16);
            op += __shfl_xor(op, 32);
        }
        if (l < 16)
            hsh[eN] = hsh[eN] + out_b[lay * EE + eN] + op;
        // next B1 (or final sync) protects the hsh update
    }

    __syncthreads();
    if (t < EE) hout[(size_t)row * EE + t] = hsh[t];
}

// ONE tail kernel: every block redundantly computes context -> query -> qk
// (2 x 128^2 FLOP, trivial), then emits logits for its 32 rows.
__global__ __launch_bounds__(512) void k_tail2(
    const float* __restrict__ hbuf,        // B*N,128
    const int*   __restrict__ open_group,  // B,N
    const float* __restrict__ context_w,   // 128,128
    const float* __restrict__ key_w,       // 128,128
    const int*   __restrict__ action_mask, // B,N
    const float* __restrict__ logit_bias,  // 1
    float* __restrict__ out)               // B,N
{
    const int b    = blockIdx.y;
    const int base = blockIdx.x * 32;      // 16 x-blocks cover 512 rows
    const int t    = threadIdx.x;
    const int e    = t & 127;
    const int s    = t >> 7;               // 0..3

    __shared__ float part[4][EE];
    __shared__ float cnt4[4];
    __shared__ float csh[EE];
    __shared__ float qsh[EE];
    __shared__ float qksh[EE];

    const float* hb = hbuf + (size_t)b * NN * EE;

    // ---- masked group-sum over n (4-way split, branch-free) ----
    {
        float gm = 0.0f, cnt = 0.0f;
        const int n0 = s * 128;
        #pragma unroll 8
        for (int u = 0; u < 128; ++u) {
            const int n = n0 + u;
            const float m = (float)open_group[b * NN + n];
            gm = fmaf(m, hb[(size_t)n * EE + e], gm);
            cnt += m;
        }
        part[s][e] = gm;
        if (e == 0) cnt4[s] = cnt;
    }
    __syncthreads();

    if (s == 0) {
        const float ca = (cnt4[0] + cnt4[1]) + (cnt4[2] + cnt4[3]);
        const float ga = (part[0][e] + part[1][e]) + (part[2][e] + part[3][e]);
        csh[e] = (ca > 0.0f) ? (ga / fmaxf(ca, 1.0f)) : hb[e];  // hb[e]=h[b,0,e]
    }
    __syncthreads();

    // ---- query[e] = context . context_w[:,e]  (split-k over s) ----
    {
        const float* cw = context_w + s * 32 * EE + e;
        float q = 0.0f;
        #pragma unroll
        for (int k = 0; k < 32; ++k)
            q = fmaf(csh[s * 32 + k], cw[k * EE], q);
        part[s][e] = q;
    }
    __syncthreads();
    if (s == 0)
        qsh[e] = (part[0][e] + part[1][e]) + (part[2][e] + part[3][e]);
    __syncthreads();

    // ---- qk[e] = key_w[e,:] . query  (split-k over s) ----
    {
        const float* kr = key_w + e * EE + s * 32;
        float a = 0.0f;
        #pragma unroll
        for (int k = 0; k < 32; ++k)
            a = fmaf(kr[k], qsh[s * 32 + k], a);
        part[s][e] = a;
    }
    __syncthreads();
    if (s == 0)
        qksh[e] = (part[0][e] + part[1][e]) + (part[2][e] + part[3][e]);
    __syncthreads();

    // ---- logits: 8 waves x 4 rows each ----
    const int wid  = t >> 6;               // 0..7
    const int lane = t & 63;
    const float q0 = qksh[lane];
    const float q1 = qksh[lane + 64];
    const float lb = logit_bias[0];

    #pragma unroll
    for (int u = 0; u < 4; ++u) {
        const int r = base + wid * 4 + u;
        const float* hr = hb + (size_t)r * EE;
        float p = hr[lane] * q0 + hr[lane + 64] * q1;
        #pragma unroll
        for (int off = 32; off; off >>= 1)
            p += __shfl_down(p, off);
        if (lane == 0) {
            float v = fmaf(p, 0.08838834764831845f, lb);   // /sqrt(128)
            out[b * NN + r] = action_mask[b * NN + r] ? v : -1000000000.0f;
        }
    }
}

extern "C" void kernel_launch(void* const* d_in, const int* in_sizes, int n_in,
                              void* d_out, int out_size, void* d_ws, size_t ws_size,
                              hipStream_t stream) {
    const float* nf         = (const float*)d_in[0];
    const float* ef         = (const float*)d_in[1];
    const float* W          = (const float*)d_in[2];
    const int*   assigned   = (const int*)d_in[3];
    const int*   open_group = (const int*)d_in[4];
    const int*   action_mask= (const int*)d_in[5];
    const float* build_limit= (const float*)d_in[6];
    const float* og_size    = (const float*)d_in[7];
    const float* embed_w    = (const float*)d_in[8];
    const float* embed_b    = (const float*)d_in[9];
    const float* node_w     = (const float*)d_in[10];
    const float* edge_w     = (const float*)d_in[11];
    const float* weight_w   = (const float*)d_in[12];
    const float* out_w      = (const float*)d_in[13];
    const float* out_b      = (const float*)d_in[14];
    const float* context_w  = (const float*)d_in[15];
    const float* key_w      = (const float*)d_in[16];
    const float* logit_bias = (const float*)d_in[17];

    float* hbuf = (float*)d_ws;                       // B*N*E floats = 1 MB

    dim3 grid_rows(NN, BB, 1);
    k_rows<<<grid_rows, 512, 0, stream>>>(nf, ef, W, assigned, open_group,
        action_mask, build_limit, og_size, embed_w, embed_b, node_w, edge_w,
        weight_w, out_w, out_b, hbuf);

    dim3 grid_tail(16, BB, 1);
    k_tail2<<<grid_tail, 512, 0, stream>>>(hbuf, open_group, context_w, key_w,
        action_mask, logit_bias, (float*)d_out);
}